// Round 2
// baseline (102.181 us; speedup 1.0000x reference)
//
#include <hip/hip_runtime.h>

// 4 items (= (n,k) pairs) per thread. Items 4t..4t+3 occupy Lgen bytes
// [144t, 144t+144) -- 144 = 9*16, so each thread issues 9 independent,
// 16B-aligned float4 loads (contiguous per-thread chunk). All 4 items
// share one point n = t>>1, so C / cofactor / dC are computed once per
// thread instead of once per item. Output: 2 aligned float4 stores.
// No LDS, no barrier; high MLP (9 loads in flight per thread).

constexpr int TPB = 256;

__global__ __launch_bounds__(TPB) void gik_kernel(
    const float* __restrict__ Lg,
    const float* __restrict__ C,
    float* __restrict__ out,
    int nThreads)  // total/4 = N*2
{
    int t = blockIdx.x * TPB + threadIdx.x;
    if (t >= nThreads) return;
    int n = t >> 1;

    // ---- issue all 9 Lgen float4 loads up front (independent, in flight) ----
    const float4* p = reinterpret_cast<const float4*>(Lg) + (size_t)t * 9;
    float4 v0 = p[0], v1 = p[1], v2 = p[2], v3 = p[3], v4 = p[4],
           v5 = p[5], v6 = p[6], v7 = p[7], v8 = p[8];

    // ---- C for this thread's point (shared by thread pairs via L1) ----
    const float* c = C + (size_t)n * 9;
    float c00 = c[0], c01 = c[1], c02 = c[2];
    float c10 = c[3], c11 = c[4], c12 = c[5];
    float c20 = c[6], c21 = c[7], c22 = c[8];

    // Cofactor matrix of C (inv(C)^T = Cof / det)
    float f00 =  (c11 * c22 - c12 * c21);
    float f01 = -(c10 * c22 - c12 * c20);
    float f02 =  (c10 * c21 - c11 * c20);
    float f10 = -(c01 * c22 - c02 * c21);
    float f11 =  (c00 * c22 - c02 * c20);
    float f12 = -(c00 * c21 - c01 * c20);
    float f20 =  (c01 * c12 - c02 * c11);
    float f21 = -(c00 * c12 - c02 * c10);
    float f22 =  (c00 * c11 - c01 * c10);

    float det  = c00 * f00 + c01 * f01 + c02 * f02;
    float rdet = 1.0f / det;

    // M = C @ inv(C)^T = C @ (Cof * rdet)
    float m00 = (c00 * f00 + c01 * f10 + c02 * f20) * rdet;
    float m01 = (c00 * f01 + c01 * f11 + c02 * f21) * rdet;
    float m02 = (c00 * f02 + c01 * f12 + c02 * f22) * rdet;
    float m10 = (c10 * f00 + c11 * f10 + c12 * f20) * rdet;
    float m11 = (c10 * f01 + c11 * f11 + c12 * f21) * rdet;
    float m12 = (c10 * f02 + c11 * f12 + c12 * f22) * rdet;
    float m20 = (c20 * f00 + c21 * f10 + c22 * f20) * rdet;
    float m21 = (c20 * f01 + c21 * f11 + c22 * f21) * rdet;
    float m22 = (c20 * f02 + c21 * f12 + c22 * f22) * rdet;

    // dC = det(M)  (analytically 1, computed faithfully)
    float dC = m00 * (m11 * m22 - m12 * m21)
             - m01 * (m10 * m22 - m12 * m20)
             + m02 * (m10 * m21 - m11 * m20);

    // ---- unpack the 36 floats into a statically-indexed array ----
    float a[36];
    a[0]=v0.x;  a[1]=v0.y;  a[2]=v0.z;  a[3]=v0.w;
    a[4]=v1.x;  a[5]=v1.y;  a[6]=v1.z;  a[7]=v1.w;
    a[8]=v2.x;  a[9]=v2.y;  a[10]=v2.z; a[11]=v2.w;
    a[12]=v3.x; a[13]=v3.y; a[14]=v3.z; a[15]=v3.w;
    a[16]=v4.x; a[17]=v4.y; a[18]=v4.z; a[19]=v4.w;
    a[20]=v5.x; a[21]=v5.y; a[22]=v5.z; a[23]=v5.w;
    a[24]=v6.x; a[25]=v6.y; a[26]=v6.z; a[27]=v6.w;
    a[28]=v7.x; a[29]=v7.y; a[30]=v7.z; a[31]=v7.w;
    a[32]=v8.x; a[33]=v8.y; a[34]=v8.z; a[35]=v8.w;

    float2 r[4];
    #pragma unroll
    for (int j = 0; j < 4; ++j) {
        const float* l = a + 9 * j;
        float I = c00 * l[0] + c01 * l[3] + c02 * l[6]
                + c10 * l[1] + c11 * l[4] + c12 * l[7]
                + c20 * l[2] + c21 * l[5] + c22 * l[8];
        float trL = l[0] + l[4] + l[8];
        r[j].x = I;
        r[j].y = dC * trL;
    }

    float4* o = reinterpret_cast<float4*>(out) + (size_t)t * 2;
    float4 w0, w1;
    w0.x = r[0].x; w0.y = r[0].y; w0.z = r[1].x; w0.w = r[1].y;
    w1.x = r[2].x; w1.y = r[2].y; w1.z = r[3].x; w1.w = r[3].y;
    o[0] = w0;
    o[1] = w1;
}

extern "C" void kernel_launch(void* const* d_in, const int* in_sizes, int n_in,
                              void* d_out, int out_size, void* d_ws, size_t ws_size,
                              hipStream_t stream) {
    const float* Lg = (const float*)d_in[0];   // [N, 8, 3, 3] f32
    const float* C  = (const float*)d_in[1];   // [N, 3, 3] f32
    float* out = (float*)d_out;                // [N, 8, 2] f32

    int N = in_sizes[1] / 9;
    int nThreads = N * 2;                      // 4 items per thread
    int blocks = (nThreads + TPB - 1) / TPB;
    gik_kernel<<<blocks, TPB, 0, stream>>>(Lg, C, out, nThreads);
}